// Round 1
// baseline (88.450 us; speedup 1.0000x reference)
//
#include <hip/hip_runtime.h>

#define I_FEAT 256
#define O_FEAT 512
#define NSEG   8
#define KDIM   (I_FEAT * NSEG)   // 2048
#define KC_N   128               // K32-chunks in Bf: [0,64) = A-half, [64,128) = bias-half
#define KCP_A  32                // meta kc-pairs (A-half only); Am stride per mt16 = KCP_A*64 uint2

typedef _Float16 half8   __attribute__((ext_vector_type(8)));
typedef float    floatx4 __attribute__((ext_vector_type(4)));
typedef uint32_t uintx4  __attribute__((ext_vector_type(4)));

// ---------------- Kernel 1: prep (LDS-free weight pack ∪ fused LN->Am), bid-split ----------------
// bid < pkTot (256): direct global->fragment pack. Block (ng=bid&7, kg=bid>>3):
//   wave w packs n16t = ng*4+w for kc = kg*4 .. kg*4+3. Each lane loads the 8 strided
//   floats of its own fragment (n = n16t*16+lane16, k = kc*32+quad*8+j), cvt->f16, store uint4.
// bid >= pkTot: LN + segment meta for one mt16 (16 rows) -> dedup Am (A-half meta only).
__global__ __launch_bounds__(256) void prep(
    const float* __restrict__ x,
    const float* __restrict__ Aw,
    const float* __restrict__ Bw,
    const float* __restrict__ gamma,
    const float* __restrict__ beta,
    uint4* __restrict__ Bf,
    uint2* __restrict__ Am,
    int Bn, int pkTot)
{
    __shared__ uint32_t M[16][260];   // LN path only (pad 260: 2-way max on emit reads)
    const int t   = threadIdx.x;
    const int bid = blockIdx.x;
    const int lane = t & 63, lane16 = lane & 15, quad = lane >> 4;

    if (bid < pkTot) {
        // ---- weight pack path (no LDS, no barrier) ----
        const int ng   = bid & 7;        // 8 groups of 64 output cols
        const int kg   = bid >> 3;       // 32 chunks of 4 kc
        const int wave = t >> 6;
        const int n16t = ng * 4 + wave;
        const int n    = n16t * 16 + lane16;
        #pragma unroll
        for (int kk = 0; kk < 4; ++kk) {
            const int kc = kg * 4 + kk;
            const int k0 = kc * 32 + quad * 8;
            const float* src = (kc < 64) ? (Aw + (size_t)k0 * O_FEAT + n)
                                         : (Bw + (size_t)(k0 - KDIM) * O_FEAT + n);
            float f[8];
            #pragma unroll
            for (int j = 0; j < 8; ++j) f[j] = src[(size_t)j * O_FEAT];
            uintx4 w;
            #pragma unroll
            for (int jj = 0; jj < 4; ++jj) {
                const uint32_t l0 = (uint32_t)__builtin_bit_cast(unsigned short, (_Float16)f[2 * jj]);
                const uint32_t h0 = (uint32_t)__builtin_bit_cast(unsigned short, (_Float16)f[2 * jj + 1]);
                w[jj] = (h0 << 16) | l0;
            }
            Bf[((size_t)n16t * KC_N + kc) * 64 + lane] = __builtin_bit_cast(uint4, w);
        }
    } else {
        // ---- LN -> Am path: one mt16 (16 rows), 16 threads per row ----
        const int mt16 = bid - pkTot;
        const int rr   = t >> 4;         // row within tile
        const int c16  = t & 15;         // 16-col group
        const int row  = mt16 * 16 + rr;
        const bool ok  = (row < Bn);

        float4 v[4];
        const float* xr = x + (size_t)row * I_FEAT + c16 * 16;
        #pragma unroll
        for (int j = 0; j < 4; ++j)
            v[j] = ok ? *(const float4*)(xr + j * 4) : make_float4(0.f, 0.f, 0.f, 0.f);

        float sum = 0.f, sq = 0.f;
        #pragma unroll
        for (int j = 0; j < 4; ++j) {
            sum += v[j].x + v[j].y + v[j].z + v[j].w;
            sq  += v[j].x * v[j].x + v[j].y * v[j].y
                 + v[j].z * v[j].z + v[j].w * v[j].w;
        }
        #pragma unroll
        for (int mask = 1; mask < 16; mask <<= 1) {   // 16-lane group reduce
            sum += __shfl_xor(sum, mask);
            sq  += __shfl_xor(sq,  mask);
        }
        const float mu  = sum * (1.0f / I_FEAT);
        const float var = sq * (1.0f / I_FEAT) - mu * mu;
        const float rs  = rsqrtf(var + 1e-5f);

        #pragma unroll
        for (int j = 0; j < 4; ++j) {
            const float4 g4 = *(const float4*)(gamma + c16 * 16 + j * 4);
            const float4 b4 = *(const float4*)(beta  + c16 * 16 + j * 4);
            const float vv[4] = { v[j].x, v[j].y, v[j].z, v[j].w };
            const float gg[4] = { g4.x, g4.y, g4.z, g4.w };
            const float bb[4] = { b4.x, b4.y, b4.z, b4.w };
            #pragma unroll
            for (int e = 0; e < 4; ++e) {
                const int c = c16 * 16 + j * 4 + e;
                float xn = (vv[e] - mu) * rs * gg[e] + bb[e];
                float fi = (xn + 1.0f) * 4.0f;   // (xn - GRID_MIN)/STEP, exact fp32
                int seg = (int)fi;                // trunc == jnp astype(int32)
                seg = seg < 0 ? 0 : (seg > NSEG - 1 ? NSEG - 1 : seg);
                _Float16 hx = (_Float16)xn;
                M[rr][c] = ((uint32_t)seg << 16)
                         | (uint32_t)__builtin_bit_cast(unsigned short, hx);
            }
        }
        __syncthreads();

        // emit dedup Am: only A-half meta (32 kcp); gemm derives the bias one-hot.
        const int g = t >> 6;
        uint2* dst = Am + (size_t)mt16 * (KCP_A * 64) + lane;
        #pragma unroll
        for (int kk = 0; kk < 8; ++kk) {
            const int kcp = g * 8 + kk;
            const int w0  = kcp * 8 + quad;      // feature of even kc; +4 for odd kc
            dst[(size_t)kcp * 64] = make_uint2(M[lane16][w0], M[lane16][w0 + 4]);
        }
    }
}

// ---------------- Kernel 2: streaming MFMA GEMM, 64m x 32n, k-split-4 ----------------
// From one meta word u = (seg<<16 | f16(xn)), build BOTH one-hots (value xn for the
// A-half, value 1.0 for the bias-half) sharing the seg decode.
static __device__ __forceinline__ void build_pair(uint32_t u, half8& ax, half8& a1) {
    const uint32_t xb  = u & 0xFFFFu;
    const uint32_t seg = u >> 16;
    const uint32_t sh  = (seg & 3u) << 4;
    const uint64_t ox  = (uint64_t)xb << sh;
    const uint64_t o1  = 0x3C00ull << sh;        // f16(1.0) at the same slot
    const bool lo = (seg < 4u);
    const uint32_t oxl = (uint32_t)ox, oxh = (uint32_t)(ox >> 32);
    const uint32_t o1l = (uint32_t)o1, o1h = (uint32_t)(o1 >> 32);
    uintx4 wx, w1;
    wx[0] = lo ? oxl : 0u;  wx[1] = lo ? oxh : 0u;
    wx[2] = lo ? 0u : oxl;  wx[3] = lo ? 0u : oxh;
    w1[0] = lo ? o1l : 0u;  w1[1] = lo ? o1h : 0u;
    w1[2] = lo ? 0u : o1l;  w1[3] = lo ? 0u : o1h;
    ax = __builtin_bit_cast(half8, wx);
    a1 = __builtin_bit_cast(half8, w1);
}

#define MFMA16 __builtin_amdgcn_mfma_f32_16x16x32_f16

__global__ __launch_bounds__(256, 2) void kan_gemm(
    const uint2* __restrict__ Am,
    const uint4* __restrict__ Bf,
    float* __restrict__ out,
    int Bn, int rt64Tot)
{
    __shared__ floatx4 s_red[4][8][64];   // 32 KB

    const int t      = threadIdx.x;
    const int wave   = t >> 6, lane = t & 63;
    const int lane16 = lane & 15, quad = lane >> 4;
    const int bid    = blockIdx.x;

    int ot, rt;
    if (rt64Tot == 32) {
        // XCD-aware decode (XCD = bid%8): per XCD 4 ot (1MB Bf) x 16 rt (1MB Am) = 2MB < L2
        const int xc = bid & 7, j = bid >> 3;
        ot = ((j >> 4) << 2) | (xc & 3);
        rt = (j & 15) | ((xc >> 2) << 4);
    } else {
        ot = bid & 15;
        rt = bid >> 4;
    }

    const uint2* pa = Am + (size_t)(rt * 4) * (KCP_A * 64) + lane;   // 4 mt16 streams
    const uint4* pb = Bf + (size_t)(ot * 2) * KC_N * 64 + lane;      // 2 n16t streams

    floatx4 acc[4][2] = {};
    const int kcp0 = wave * 8;   // 4-way kc-pair split over the A-half

    #pragma unroll 2
    for (int p = 0; p < 8; ++p) {
        const int kcp = kcp0 + p;
        const uint2 u0 = pa[(size_t)(kcp * 64)];
        const uint2 u1 = pa[(size_t)(2048 + kcp * 64)];
        const uint2 u2 = pa[(size_t)(4096 + kcp * 64)];
        const uint2 u3 = pa[(size_t)(6144 + kcp * 64)];
        const int kb = 2 * kcp;
        // A-half fragments (even/odd kc) and matching bias-half fragments (+64 kc)
        const half8 e0  = __builtin_bit_cast(half8, pb[(size_t)((kb)      * 64)]);
        const half8 q0  = __builtin_bit_cast(half8, pb[(size_t)((kb + 1)  * 64)]);
        const half8 be0 = __builtin_bit_cast(half8, pb[(size_t)((kb + 64) * 64)]);
        const half8 bq0 = __builtin_bit_cast(half8, pb[(size_t)((kb + 65) * 64)]);
        const half8 e1  = __builtin_bit_cast(half8, pb[(size_t)(8192 + (kb)      * 64)]);
        const half8 q1  = __builtin_bit_cast(half8, pb[(size_t)(8192 + (kb + 1)  * 64)]);
        const half8 be1 = __builtin_bit_cast(half8, pb[(size_t)(8192 + (kb + 64) * 64)]);
        const half8 bq1 = __builtin_bit_cast(half8, pb[(size_t)(8192 + (kb + 65) * 64)]);

        half8 ax, av;
#define ROWOP(r, uu) \
        build_pair(uu.x, ax, av); \
        acc[r][0] = MFMA16(ax, e0,  acc[r][0], 0, 0, 0); \
        acc[r][1] = MFMA16(ax, e1,  acc[r][1], 0, 0, 0); \
        acc[r][0] = MFMA16(av, be0, acc[r][0], 0, 0, 0); \
        acc[r][1] = MFMA16(av, be1, acc[r][1], 0, 0, 0); \
        build_pair(uu.y, ax, av); \
        acc[r][0] = MFMA16(ax, q0,  acc[r][0], 0, 0, 0); \
        acc[r][1] = MFMA16(ax, q1,  acc[r][1], 0, 0, 0); \
        acc[r][0] = MFMA16(av, bq0, acc[r][0], 0, 0, 0); \
        acc[r][1] = MFMA16(av, bq1, acc[r][1], 0, 0, 0);

        ROWOP(0, u0)
        ROWOP(1, u1)
        ROWOP(2, u2)
        ROWOP(3, u3)
#undef ROWOP
    }

    // cross-wave kc reduction: every wave dumps all 8 tiles, then sums 2 tiles.
    #pragma unroll
    for (int mi = 0; mi < 4; ++mi)
        #pragma unroll
        for (int ni = 0; ni < 2; ++ni)
            s_red[wave][mi * 2 + ni][lane] = acc[mi][ni];
    __syncthreads();

    #pragma unroll
    for (int q = 0; q < 2; ++q) {
        const int tt = wave * 2 + q;
        const int mi = tt >> 1, ni = tt & 1;
        floatx4 vsum = s_red[0][tt][lane];
        vsum += s_red[1][tt][lane];
        vsum += s_red[2][tt][lane];
        vsum += s_red[3][tt][lane];
        const int gcol = ot * 32 + ni * 16 + lane16;
        const int gr0  = rt * 64 + mi * 16 + quad * 4;
        #pragma unroll
        for (int r = 0; r < 4; ++r) {
            const int grow = gr0 + r;
            if (grow < Bn)
                out[(size_t)grow * O_FEAT + gcol] = vsum[r];
        }
    }
}

extern "C" void kernel_launch(void* const* d_in, const int* in_sizes, int n_in,
                              void* d_out, int out_size, void* d_ws, size_t ws_size,
                              hipStream_t stream) {
    const float* x   = (const float*)d_in[0];
    const float* Aw  = (const float*)d_in[1];
    const float* Bw  = (const float*)d_in[2];
    const float* gam = (const float*)d_in[3];
    const float* bet = (const float*)d_in[4];
    float* out       = (float*)d_out;

    const int Bn      = in_sizes[0] / I_FEAT;
    const int mt16Tot = (Bn + 15) / 16;
    const int rt64Tot = (Bn + 63) / 64;
    const int pkTot   = 256;   // 8 n-groups x 32 kc-chunks

    // ws: Bf 4MB | Am (mt16Tot * KCP_A*64 * 8B = 2MB @ Bn=2048)
    uint4* Bf = (uint4*)d_ws;
    uint2* Am = (uint2*)(Bf + (size_t)(O_FEAT / 16) * KC_N * 64);

    hipLaunchKernelGGL(prep, dim3(pkTot + mt16Tot), dim3(256), 0, stream,
                       x, Aw, Bw, gam, bet, Bf, Am, Bn, pkTot);
    hipLaunchKernelGGL(kan_gemm, dim3(16 * rt64Tot), dim3(256), 0, stream,
                       Am, Bf, out, Bn, rt64Tot);
}